// Round 6
// baseline (442.147 us; speedup 1.0000x reference)
//
#include <hip/hip_runtime.h>

constexpr int N   = 100000;   // nodes
constexpr int E   = 1600000;  // message edges
constexpr int EP  = 200000;   // pos scored edges
constexpr int ES  = 400000;   // total scored edges (pos+neg)
constexpr int CAP = 64;       // per-node in-edge bucket capacity (Poisson(16): P(deg>=64)~1e-18)
constexpr int XG2 = 64;       // radix groups (round-17: 8 -> 64 for temporal write staging)
constexpr int DR2 = (N + XG2 - 1) / XG2;    // 1563 nodes per group
constexpr int NH  = N / 2;    // agg1 half-range (profiling visibility split)
constexpr int SEGCAP = 26624; // per-group segment capacity (E/64=25000 mean, +10 sigma; x256)
constexpr int BPS = SEGCAP / 256;           // 104 pass-B blocks per subgroup
constexpr int EPB = 8192;     // edges per partition block
constexpr int PBS = 1024;     // partition block size
constexpr int NPB = (E + EPB - 1) / EPB;    // 196 partition blocks
constexpr int BSTR = 264;     // gemm1 LDS B k-stride (f16): 264*2B=528B -> bank (4n+4q)%32, 2-way max

typedef _Float16 f16x8 __attribute__((ext_vector_type(8)));
typedef _Float16 f16x4 __attribute__((ext_vector_type(4)));
typedef _Float16 f16x2 __attribute__((ext_vector_type(2)));
typedef float    f32x4 __attribute__((ext_vector_type(4)));

// ---------------------------------------------------------------- Pass A: partition edges
// Round-14 structure (196 blocks x 8192 edges, LDS histogram + ONE global
// atomic per group per block). Round-17: 64 groups instead of 8 — pass-B
// write-merge staging (see fill_buckets2). pack = rel(11b) << 17 | src(17b).
__global__ __launch_bounds__(1024) void partition_edges(const int* __restrict__ ei,
                                                        int* __restrict__ gcnt,
                                                        unsigned* __restrict__ eb) {
    __shared__ int lh[XG2];   // block histogram
    __shared__ int rk[XG2];   // running rank counters (init = global base)
    const int tid = threadIdx.x;
    const int e0  = blockIdx.x * EPB;
    if (tid < XG2) lh[tid] = 0;
    __syncthreads();
#pragma unroll
    for (int i = 0; i < EPB; i += PBS) {
        const int e = e0 + i + tid;
        if (e < E) {
            const int d = ei[E + e];
            atomicAdd(&lh[d / DR2], 1);
        }
    }
    __syncthreads();
    if (tid < XG2) rk[tid] = atomicAdd(&gcnt[tid], lh[tid]);  // one hot atomic per group per block
    __syncthreads();
#pragma unroll
    for (int i = 0; i < EPB; i += PBS) {
        const int e = e0 + i + tid;
        if (e < E) {
            const int s   = ei[e];
            const int d   = ei[E + e];
            const int g   = d / DR2;
            const int rel = d - g * DR2;               // < 1563 < 2^11
            const int p   = atomicAdd(&rk[g], 1);
            if (p < SEGCAP)
                eb[(size_t)g * SEGCAP + p] = ((unsigned)rel << 17) | (unsigned)s;
        }
    }
}

// ---------------------------------------------------------------- Pass B: bucket fill
// Round-17: round-16 showed WRITE 63MB for 6.4MB payload (each 4B scatter
// store retired as its own ~32B HBM sector; dur x 1.02TB/s == hbm_bytes ->
// scattered-write-BW-bound). Fix: 64 subgroups, XCD x walks its 8 subgroups
// SEQUENTIALLY (g = x*8 + j/BPS) so the live dirty col footprint per XCD is
// ~400KB per stage instead of 3.2MB over the whole kernel — a node's ~16
// entries now merge in L2 before eviction (expect WRITE ~13-18MB).
__global__ __launch_bounds__(256) void fill_buckets2(const unsigned* __restrict__ eb,
                                                     const int* __restrict__ gcnt,
                                                     int* __restrict__ cnt,
                                                     int* __restrict__ col) {
    const int x   = blockIdx.x & 7;            // XCD (round-robin dispatch)
    const int j   = blockIdx.x >> 3;           // 0 .. 8*BPS-1
    const int s7  = j / BPS;                   // stage 0..7
    const int g   = x * 8 + s7;                // subgroup
    const int idx = (j - s7 * BPS) * 256 + threadIdx.x;
    const int cg  = min(gcnt[g], SEGCAP);
    if (idx >= cg) return;
    const unsigned pack = __builtin_nontemporal_load(&eb[(size_t)g * SEGCAP + idx]);
    const int s = (int)(pack & 0x1FFFFu);
    const int d = (int)(pack >> 17) + g * DR2;
    const int p = atomicAdd(&cnt[d], 1);
    if (p < CAP) col[d * CAP + p] = s;         // NOT nontemporal: must linger in L2 to merge
}

// ---------------------------------------------------------------- W1 transpose prep
// W1T[n][k] = (f16)W1[k][n]  (128 x 256 f16 = 64KB). One-time ~2us.
__global__ __launch_bounds__(256) void w1_transpose(const float* __restrict__ W1,
                                                    _Float16* __restrict__ W1T) {
    const int n = blockIdx.x;          // 0..127
    const int k = threadIdx.x;         // 0..255
    W1T[n * 256 + k] = (_Float16)W1[(size_t)k * 128 + n];
}

// ---------------------------------------------------------------- GEMM1 (f16 MFMA)
// Round-15/16: B-stationary, ZERO barriers in K-loop; whole W1T in padded
// LDS; A streams global->reg->f16 nontemporal; M_rep=4 -> 32 MFMA per
// 8 ds_read_b128 + 8 global dwordx4 per k-step. Dropped out of top-5.
__global__ __launch_bounds__(256) void gemm1_mfma(const float* __restrict__ X,
                                                  const _Float16* __restrict__ W1T,
                                                  _Float16* __restrict__ H) {
    __shared__ _Float16 Bs[128][BSTR];   // 67.6 KB -> 2 blocks/CU

    const int tid  = threadIdx.x;
    const int wave = tid >> 6;
    const int lane = tid & 63;
    const int m16  = lane & 15;
    const int quad = lane >> 4;
    const int rowBase = blockIdx.x * 256 + wave * 64;

    // ---- preload whole W1T into LDS (16 x b128 per thread), once
#pragma unroll
    for (int i = 0; i < 16; ++i) {
        const int c  = tid + 256 * i;         // 4096 chunks of 16B
        const int n  = c >> 5;                // row (col of W1)
        const int kb = (c & 31) * 16;         // byte within row
        *(f16x8*)((char*)&Bs[n][0] + kb) = *(const f16x8*)((const char*)W1T + (size_t)c * 16);
    }
    __syncthreads();   // the only barrier in the kernel

    f32x4 acc[4][8] = {};
    f32x4 avA[8];

    auto loadA = [&](int k0) {
#pragma unroll
        for (int m = 0; m < 4; ++m) {
            int gr = rowBase + m * 16 + m16;
            gr = gr < N ? gr : N - 1;         // clamp (stores guarded)
            const f32x4* p = (const f32x4*)&X[(size_t)gr * 256 + k0 + quad * 8];
            avA[2 * m]     = __builtin_nontemporal_load(p);
            avA[2 * m + 1] = __builtin_nontemporal_load(p + 1);
        }
    };

    loadA(0);
    for (int k0 = 0; k0 < 256; k0 += 32) {
        f16x8 af[4];
#pragma unroll
        for (int m = 0; m < 4; ++m) {
            f16x8 h;
            h[0] = (_Float16)avA[2*m][0];   h[1] = (_Float16)avA[2*m][1];
            h[2] = (_Float16)avA[2*m][2];   h[3] = (_Float16)avA[2*m][3];
            h[4] = (_Float16)avA[2*m+1][0]; h[5] = (_Float16)avA[2*m+1][1];
            h[6] = (_Float16)avA[2*m+1][2]; h[7] = (_Float16)avA[2*m+1][3];
            af[m] = h;
        }
        if (k0 + 32 < 256) loadA(k0 + 32);    // prefetch next tile into regs
#pragma unroll
        for (int nt = 0; nt < 8; ++nt) {
            const f16x8 bf = *(const f16x8*)&Bs[nt * 16 + m16][k0 + quad * 8];
#pragma unroll
            for (int m = 0; m < 4; ++m)
                acc[m][nt] = __builtin_amdgcn_mfma_f32_16x16x32_f16(af[m], bf, acc[m][nt], 0, 0, 0);
        }
    }

    // ---- epilogue: C/D layout col=lane&15, row=quad*4+r (verified convention)
#pragma unroll
    for (int m = 0; m < 4; ++m)
#pragma unroll
        for (int nt = 0; nt < 8; ++nt)
#pragma unroll
            for (int r = 0; r < 4; ++r) {
                const int gm = rowBase + m * 16 + quad * 4 + r;
                if (gm < N) H[(size_t)gm * 128 + nt * 16 + m16] = (_Float16)acc[m][nt][r];
            }
}

// ---------------------------------------------------------------- Fused agg1 + gemm2
// One wave per node; lane l owns feats [2l, 2l+1]; depth-4 double-buffered
// prefetch (proven best). Two half-range launches for profiler visibility.
__global__ __launch_bounds__(256) void agg1_gemm2(const _Float16* __restrict__ H,
                                                  const int* __restrict__ cnt,
                                                  const int* __restrict__ col,
                                                  const float* __restrict__ b1,
                                                  const float* __restrict__ W2,
                                                  float* __restrict__ Z,
                                                  int nbase, int ncount) {
    const int nr   = (blockIdx.x * blockDim.x + threadIdx.x) >> 6;
    const int lane = threadIdx.x & 63;
    if (nr >= ncount) return;
    const int n = nbase + nr;
    const int c = min(cnt[n], CAP);

    int sv = n;
    if (lane < c) sv = col[n * CAP + lane];
    const float dvw = rsqrtf((float)cnt[sv] + 1.0f);
    const float dv  = (lane <= c) ? dvw : 0.0f;

    const _Float16* hbase = H + lane * 2;
    const int ned4 = (c + 1 + 3) & ~3;

    f16x2 va[4]; float wa[4];
#pragma unroll
    for (int t = 0; t < 4; ++t) {
        const int   e = min(t, 63);
        const int   s = __shfl(sv, e);
        wa[t]         = __shfl(dv, e);
        va[t] = *(const f16x2*)&hbase[(size_t)s * 128];
    }
    float ax = 0.f, ay = 0.f;
    for (int j = 4; j < ned4; j += 4) {
        f16x2 vb[4]; float wb[4];
#pragma unroll
        for (int t = 0; t < 4; ++t) {
            const int   e = min(j + t, 63);
            const int   s = __shfl(sv, e);
            wb[t]         = __shfl(dv, e);
            vb[t] = *(const f16x2*)&hbase[(size_t)s * 128];
        }
#pragma unroll
        for (int t = 0; t < 4; ++t) {
            ax = fmaf(wa[t], (float)va[t][0], ax);
            ay = fmaf(wa[t], (float)va[t][1], ay);
            va[t] = vb[t]; wa[t] = wb[t];
        }
    }
#pragma unroll
    for (int t = 0; t < 4; ++t) {
        ax = fmaf(wa[t], (float)va[t][0], ax);
        ay = fmaf(wa[t], (float)va[t][1], ay);
    }

    const float dn = __shfl(dv, c);         // dinv[n]
    const float2 b = *(const float2*)&b1[lane * 2];
    const float hr0 = fmaxf(ax * dn + b.x, 0.f);
    const float hr1 = fmaxf(ay * dn + b.y, 0.f);

    const float4 wa0 = *(const float4*)&W2[(size_t)(lane * 2) * 8];
    const float4 wa1 = *(const float4*)&W2[(size_t)(lane * 2) * 8 + 4];
    const float4 wb0 = *(const float4*)&W2[(size_t)(lane * 2 + 1) * 8];
    const float4 wb1 = *(const float4*)&W2[(size_t)(lane * 2 + 1) * 8 + 4];
    float p[8];
    p[0] = hr0 * wa0.x + hr1 * wb0.x;
    p[1] = hr0 * wa0.y + hr1 * wb0.y;
    p[2] = hr0 * wa0.z + hr1 * wb0.z;
    p[3] = hr0 * wa0.w + hr1 * wb0.w;
    p[4] = hr0 * wa1.x + hr1 * wb1.x;
    p[5] = hr0 * wa1.y + hr1 * wb1.y;
    p[6] = hr0 * wa1.z + hr1 * wb1.z;
    p[7] = hr0 * wa1.w + hr1 * wb1.w;
#pragma unroll
    for (int off = 32; off > 0; off >>= 1)
#pragma unroll
        for (int j = 0; j < 8; ++j) p[j] += __shfl_xor(p[j], off);
    if (lane == 0) {
        *(float4*)&Z[(size_t)n * 8]     = make_float4(p[0], p[1], p[2], p[3]);
        *(float4*)&Z[(size_t)n * 8 + 4] = make_float4(p[4], p[5], p[6], p[7]);
    }
}

// ---------------------------------------------------------------- Aggregation layer 2 (F=8)
__global__ __launch_bounds__(64) void agg2(const float* __restrict__ Z,
                                           const int* __restrict__ cnt,
                                           const int* __restrict__ col,
                                           const float* __restrict__ b2,
                                           float* __restrict__ ZA) {
    const int n = blockIdx.x * blockDim.x + threadIdx.x;
    if (n >= N) return;
    const int c = min(cnt[n], CAP);
    float acc[8] = {};

    float4 va0[4], va1[4]; float wv[4];
#pragma unroll
    for (int t = 0; t < 4; ++t) {
        const int s = (t < c) ? col[n * CAP + t] : n;
        wv[t]  = (t < c) ? rsqrtf((float)cnt[s] + 1.0f) : 0.0f;
        va0[t] = *(const float4*)&Z[(size_t)s * 8];
        va1[t] = *(const float4*)&Z[(size_t)s * 8 + 4];
    }
    for (int j = 4; j + 4 <= c + 4; j += 4) {
        float4 vb0[4], vb1[4]; float wb[4];
#pragma unroll
        for (int t = 0; t < 4; ++t) {
            const int jt = j + t;
            const int s  = (jt < c) ? col[n * CAP + jt] : n;
            wb[t]  = (jt < c) ? rsqrtf((float)cnt[s] + 1.0f) : 0.0f;
            vb0[t] = *(const float4*)&Z[(size_t)s * 8];
            vb1[t] = *(const float4*)&Z[(size_t)s * 8 + 4];
        }
#pragma unroll
        for (int t = 0; t < 4; ++t) {
            const float w = wv[t];
            acc[0] = fmaf(w, va0[t].x, acc[0]); acc[1] = fmaf(w, va0[t].y, acc[1]);
            acc[2] = fmaf(w, va0[t].z, acc[2]); acc[3] = fmaf(w, va0[t].w, acc[3]);
            acc[4] = fmaf(w, va1[t].x, acc[4]); acc[5] = fmaf(w, va1[t].y, acc[5]);
            acc[6] = fmaf(w, va1[t].z, acc[6]); acc[7] = fmaf(w, va1[t].w, acc[7]);
            va0[t] = vb0[t]; va1[t] = vb1[t]; wv[t] = wb[t];
        }
    }
#pragma unroll
    for (int t = 0; t < 4; ++t) {
        const float w = wv[t];
        acc[0] = fmaf(w, va0[t].x, acc[0]); acc[1] = fmaf(w, va0[t].y, acc[1]);
        acc[2] = fmaf(w, va0[t].z, acc[2]); acc[3] = fmaf(w, va0[t].w, acc[3]);
        acc[4] = fmaf(w, va1[t].x, acc[4]); acc[5] = fmaf(w, va1[t].y, acc[5]);
        acc[6] = fmaf(w, va1[t].z, acc[6]); acc[7] = fmaf(w, va1[t].w, acc[7]);
    }

    const float dn = rsqrtf((float)c + 1.0f);
    const float4 zn0 = *(const float4*)&Z[(size_t)n * 8];
    const float4 zn1 = *(const float4*)&Z[(size_t)n * 8 + 4];
    float o[8];
    o[0] = (acc[0] + dn * zn0.x) * dn + b2[0];
    o[1] = (acc[1] + dn * zn0.y) * dn + b2[1];
    o[2] = (acc[2] + dn * zn0.z) * dn + b2[2];
    o[3] = (acc[3] + dn * zn0.w) * dn + b2[3];
    o[4] = (acc[4] + dn * zn1.x) * dn + b2[4];
    o[5] = (acc[5] + dn * zn1.y) * dn + b2[5];
    o[6] = (acc[6] + dn * zn1.z) * dn + b2[6];
    o[7] = (acc[7] + dn * zn1.w) * dn + b2[7];
    *(float4*)&ZA[(size_t)n * 8]     = make_float4(o[0], o[1], o[2], o[3]);
    *(float4*)&ZA[(size_t)n * 8 + 4] = make_float4(o[4], o[5], o[6], o[7]);
}

// ---------------------------------------------------------------- Edge scoring
__global__ __launch_bounds__(256) void score(const float* __restrict__ ZA,
                                             const int* __restrict__ pe,
                                             const int* __restrict__ ne,
                                             float* __restrict__ out) {
    const int e = blockIdx.x * blockDim.x + threadIdx.x;
    if (e >= ES) return;
    int a, b;
    if (e < EP) { a = pe[e];      b = pe[EP + e]; }
    else        { a = ne[e - EP]; b = ne[e];      }
    const float4 xa0 = *(const float4*)&ZA[(size_t)a * 8];
    const float4 xa1 = *(const float4*)&ZA[(size_t)a * 8 + 4];
    const float4 xb0 = *(const float4*)&ZA[(size_t)b * 8];
    const float4 xb1 = *(const float4*)&ZA[(size_t)b * 8 + 4];
    out[e] = xa0.x * xb0.x + xa0.y * xb0.y + xa0.z * xb0.z + xa0.w * xb0.w +
             xa1.x * xb1.x + xa1.y * xb1.y + xa1.z * xb1.z + xa1.w * xb1.w;
}

// ---------------------------------------------------------------- launch

extern "C" void kernel_launch(void* const* d_in, const int* in_sizes, int n_in,
                              void* d_out, int out_size, void* d_ws, size_t ws_size,
                              hipStream_t stream) {
    const float* x  = (const float*)d_in[0];
    const int*   ei = (const int*)d_in[1];   // [2, 1.6M] row-major
    const int*   pe = (const int*)d_in[2];   // [2, 200k]
    const int*   ne = (const int*)d_in[3];   // [2, 200k]
    const float* W1 = (const float*)d_in[4];
    const float* b1 = (const float*)d_in[5];
    const float* W2 = (const float*)d_in[6];
    const float* b2 = (const float*)d_in[7];
    float* out = (float*)d_out;

    char* ws = (char*)d_ws;
    size_t off = 0;
    auto carve = [&](size_t bytes) {
        char* p = ws + off;
        off += (bytes + 255) & ~(size_t)255;
        return p;
    };
    int*       cnt  = (int*)      carve((size_t)N * sizeof(int));            // 0.4 MB
    int*       gcnt = (int*)      carve((size_t)XG2 * sizeof(int));          // 256 B (adjacent to cnt)
    unsigned*  eb   = (unsigned*) carve((size_t)XG2 * SEGCAP * sizeof(unsigned)); // 6.8 MB
    int*       col  = (int*)      carve((size_t)N * CAP * sizeof(int));      // 25.6 MB
    _Float16*  H    = (_Float16*) carve((size_t)N * 128 * sizeof(_Float16)); // 25.6 MB
    float*     Z    = (float*)    carve((size_t)N * 8 * sizeof(float));      // 3.2 MB
    float*     ZA   = (float*)    carve((size_t)N * 8 * sizeof(float));      // 3.2 MB
    _Float16*  W1T  = (_Float16*) carve((size_t)128 * 256 * sizeof(_Float16)); // 64 KB

    // one memset covers cnt + gcnt (gcnt carved immediately after cnt)
    hipMemsetAsync(cnt, 0, (size_t)((char*)gcnt - (char*)cnt) + XG2 * sizeof(int), stream);
    partition_edges<<<NPB, PBS, 0, stream>>>(ei, gcnt, eb);
    w1_transpose   <<<128, 256, 0, stream>>>(W1, W1T);
    fill_buckets2  <<<8 * 8 * BPS, 256, 0, stream>>>(eb, gcnt, cnt, col);
    gemm1_mfma     <<<(N + 255) / 256, 256, 0, stream>>>(x, W1T, H);
    agg1_gemm2     <<<(NH * 64 + 255) / 256, 256, 0, stream>>>(H, cnt, col, b1, W2, Z, 0, NH);
    agg1_gemm2     <<<((N - NH) * 64 + 255) / 256, 256, 0, stream>>>(H, cnt, col, b1, W2, Z, NH, N - NH);
    agg2           <<<(N + 63) / 64, 64, 0, stream>>>(Z, cnt, col, b2, ZA);
    score          <<<(ES + 255) / 256, 256, 0, stream>>>(ZA, pe, ne, out);
}

// Round 7
// 358.979 us; speedup vs baseline: 1.2317x; 1.2317x over previous
//
#include <hip/hip_runtime.h>

constexpr int N   = 100000;   // nodes
constexpr int E   = 1600000;  // message edges
constexpr int EP  = 200000;   // pos scored edges
constexpr int ES  = 400000;   // total scored edges (pos+neg)
constexpr int CAP = 64;       // per-node fan-in clamp for lane-gather (Poisson(16): P(deg>64)~1e-18)
constexpr int XG2 = 128;      // radix groups (round-19: CSR counting-sort fill)
constexpr int DR2 = (N + XG2 - 1) / XG2;    // 782 nodes per group
constexpr int NH  = N / 2;    // agg1 half-range (profiling visibility split)
constexpr int SEGCAP = 14336; // per-group segment capacity (E/128=12500 mean, +16 sigma)
constexpr int EPB = 8192;     // edges per partition block
constexpr int PBS = 1024;     // partition block size
constexpr int NPB = (E + EPB - 1) / EPB;    // 196 partition blocks
constexpr int BSTR = 264;     // gemm1 LDS B k-stride (f16): 264*2B=528B -> bank (4n+4q)%32, 2-way max

typedef _Float16 f16x8 __attribute__((ext_vector_type(8)));
typedef _Float16 f16x4 __attribute__((ext_vector_type(4)));
typedef _Float16 f16x2 __attribute__((ext_vector_type(2)));
typedef float    f32x4 __attribute__((ext_vector_type(4)));

// ---------------------------------------------------------------- Pass A: partition edges
// Round-14 structure (196 blocks x 8192 edges, LDS histogram + ONE global
// atomic per group per block). Round-19: 128 groups; pack = rel(10b)<<17 | src(17b).
__global__ __launch_bounds__(1024) void partition_edges(const int* __restrict__ ei,
                                                        int* __restrict__ gcnt,
                                                        unsigned* __restrict__ eb) {
    __shared__ int lh[XG2];   // block histogram
    __shared__ int rk[XG2];   // running rank counters (init = global base)
    const int tid = threadIdx.x;
    const int e0  = blockIdx.x * EPB;
    if (tid < XG2) lh[tid] = 0;
    __syncthreads();
#pragma unroll
    for (int i = 0; i < EPB; i += PBS) {
        const int e = e0 + i + tid;
        if (e < E) {
            const int d = ei[E + e];
            atomicAdd(&lh[d / DR2], 1);
        }
    }
    __syncthreads();
    if (tid < XG2) rk[tid] = atomicAdd(&gcnt[tid], lh[tid]);  // one hot atomic per group per block
    __syncthreads();
#pragma unroll
    for (int i = 0; i < EPB; i += PBS) {
        const int e = e0 + i + tid;
        if (e < E) {
            const int s   = ei[e];
            const int d   = ei[E + e];
            const int g   = d / DR2;
            const int rel = d - g * DR2;               // < 782 < 2^10
            const int p   = atomicAdd(&rk[g], 1);
            if (p < SEGCAP)
                eb[(size_t)g * SEGCAP + p] = ((unsigned)rel << 17) | (unsigned)s;
        }
    }
}

// ---------------------------------------------------------------- Pass B: CSR counting sort
// Round-19: rounds 16/18 proved 4B scattered col stores CANNOT be merged by
// L2 (WRITE 63MB / 52MB for 6.4MB payload; staging made it WORSE: 67->91us).
// Structural fix: one 1024-thread block per group finishes the sort in LDS
// and writes EVERYTHING coalesced: (1) LDS histogram over 782 node slots,
// (2) shfl exclusive scan -> per-node offsets; cnt + rowptr written
// coalesced (no global atomics, no cnt memset), (3) re-read segment
// (L2-warm), scatter src into LDS stage at ranked positions, (4) stage ->
// colc as full lines. LDS = 57.3KB stage + 4KB hist = 61.5KB.
__global__ __launch_bounds__(1024) void fill_csr(const unsigned* __restrict__ eb,
                                                 const int* __restrict__ gcnt,
                                                 int* __restrict__ cnt,
                                                 int* __restrict__ rp,
                                                 int* __restrict__ colc) {
    __shared__ int hcnt[1024];          // counts -> cursors (DR2=782 used)
    __shared__ int wsum[16];
    __shared__ unsigned stage[SEGCAP];  // 57.3 KB
    const int g   = blockIdx.x;
    const int tid = threadIdx.x;
    const int cg  = min(gcnt[g], SEGCAP);
    const unsigned* seg = eb + (size_t)g * SEGCAP;

    hcnt[tid] = 0;
    __syncthreads();
    for (int i = tid; i < cg; i += 1024)
        atomicAdd(&hcnt[seg[i] >> 17], 1);
    __syncthreads();

    // exclusive scan over 1024 counters (wave scan + wave-sum scan)
    const int c    = hcnt[tid];
    const int lane = tid & 63;
    const int wid  = tid >> 6;
    int incl = c;
#pragma unroll
    for (int off = 1; off < 64; off <<= 1) {
        const int v = __shfl_up(incl, off);
        if (lane >= off) incl += v;
    }
    if (lane == 63) wsum[wid] = incl;
    __syncthreads();
    if (tid < 16) {
        int v = wsum[tid];
#pragma unroll
        for (int off = 1; off < 16; off <<= 1) {
            const int u = __shfl_up(v, off);
            if (tid >= off) v += u;
        }
        wsum[tid] = v;   // inclusive wave sums
    }
    __syncthreads();
    const int excl = incl - c + (wid ? wsum[wid - 1] : 0);

    const int base = g * DR2;
    if (tid < DR2 && base + tid < N) {
        cnt[base + tid] = c;                       // full in-degree
        rp [base + tid] = g * SEGCAP + excl;       // CSR row start
    }
    __syncthreads();       // scan reads done before cursor overwrite
    hcnt[tid] = excl;
    __syncthreads();

    for (int i = tid; i < cg; i += 1024) {
        const unsigned pk = seg[i];
        const int p = atomicAdd(&hcnt[pk >> 17], 1);
        stage[p] = pk & 0x1FFFFu;
    }
    __syncthreads();
    for (int i = tid; i < cg; i += 1024)
        colc[(size_t)g * SEGCAP + i] = (int)stage[i];   // full-line streaming writes
}

// ---------------------------------------------------------------- W1 transpose prep
// W1T[n][k] = (f16)W1[k][n]  (128 x 256 f16 = 64KB). One-time ~2us.
__global__ __launch_bounds__(256) void w1_transpose(const float* __restrict__ W1,
                                                    _Float16* __restrict__ W1T) {
    const int n = blockIdx.x;          // 0..127
    const int k = threadIdx.x;         // 0..255
    W1T[n * 256 + k] = (_Float16)W1[(size_t)k * 128 + n];
}

// ---------------------------------------------------------------- GEMM1 (f16 MFMA)
// Round-15/16: B-stationary, ZERO barriers in K-loop; whole W1T in padded
// LDS; A streams global->reg->f16 nontemporal; M_rep=4 -> 32 MFMA per
// 8 ds_read_b128 + 8 global dwordx4 per k-step. Dropped out of top-5.
__global__ __launch_bounds__(256) void gemm1_mfma(const float* __restrict__ X,
                                                  const _Float16* __restrict__ W1T,
                                                  _Float16* __restrict__ H) {
    __shared__ _Float16 Bs[128][BSTR];   // 67.6 KB -> 2 blocks/CU

    const int tid  = threadIdx.x;
    const int wave = tid >> 6;
    const int lane = tid & 63;
    const int m16  = lane & 15;
    const int quad = lane >> 4;
    const int rowBase = blockIdx.x * 256 + wave * 64;

    // ---- preload whole W1T into LDS (16 x b128 per thread), once
#pragma unroll
    for (int i = 0; i < 16; ++i) {
        const int c  = tid + 256 * i;         // 4096 chunks of 16B
        const int n  = c >> 5;                // row (col of W1)
        const int kb = (c & 31) * 16;         // byte within row
        *(f16x8*)((char*)&Bs[n][0] + kb) = *(const f16x8*)((const char*)W1T + (size_t)c * 16);
    }
    __syncthreads();   // the only barrier in the kernel

    f32x4 acc[4][8] = {};
    f32x4 avA[8];

    auto loadA = [&](int k0) {
#pragma unroll
        for (int m = 0; m < 4; ++m) {
            int gr = rowBase + m * 16 + m16;
            gr = gr < N ? gr : N - 1;         // clamp (stores guarded)
            const f32x4* p = (const f32x4*)&X[(size_t)gr * 256 + k0 + quad * 8];
            avA[2 * m]     = __builtin_nontemporal_load(p);
            avA[2 * m + 1] = __builtin_nontemporal_load(p + 1);
        }
    };

    loadA(0);
    for (int k0 = 0; k0 < 256; k0 += 32) {
        f16x8 af[4];
#pragma unroll
        for (int m = 0; m < 4; ++m) {
            f16x8 h;
            h[0] = (_Float16)avA[2*m][0];   h[1] = (_Float16)avA[2*m][1];
            h[2] = (_Float16)avA[2*m][2];   h[3] = (_Float16)avA[2*m][3];
            h[4] = (_Float16)avA[2*m+1][0]; h[5] = (_Float16)avA[2*m+1][1];
            h[6] = (_Float16)avA[2*m+1][2]; h[7] = (_Float16)avA[2*m+1][3];
            af[m] = h;
        }
        if (k0 + 32 < 256) loadA(k0 + 32);    // prefetch next tile into regs
#pragma unroll
        for (int nt = 0; nt < 8; ++nt) {
            const f16x8 bf = *(const f16x8*)&Bs[nt * 16 + m16][k0 + quad * 8];
#pragma unroll
            for (int m = 0; m < 4; ++m)
                acc[m][nt] = __builtin_amdgcn_mfma_f32_16x16x32_f16(af[m], bf, acc[m][nt], 0, 0, 0);
        }
    }

    // ---- epilogue: C/D layout col=lane&15, row=quad*4+r (verified convention)
#pragma unroll
    for (int m = 0; m < 4; ++m)
#pragma unroll
        for (int nt = 0; nt < 8; ++nt)
#pragma unroll
            for (int r = 0; r < 4; ++r) {
                const int gm = rowBase + m * 16 + quad * 4 + r;
                if (gm < N) H[(size_t)gm * 128 + nt * 16 + m16] = (_Float16)acc[m][nt][r];
            }
}

// ---------------------------------------------------------------- Fused agg1 + gemm2
// One wave per node; lane l owns feats [2l, 2l+1]; depth-4 double-buffered
// prefetch (proven best). Round-19: CSR gather via rp[] instead of CAP stride.
__global__ __launch_bounds__(256) void agg1_gemm2(const _Float16* __restrict__ H,
                                                  const int* __restrict__ cnt,
                                                  const int* __restrict__ rp,
                                                  const int* __restrict__ colc,
                                                  const float* __restrict__ b1,
                                                  const float* __restrict__ W2,
                                                  float* __restrict__ Z,
                                                  int nbase, int ncount) {
    const int nr   = (blockIdx.x * blockDim.x + threadIdx.x) >> 6;
    const int lane = threadIdx.x & 63;
    if (nr >= ncount) return;
    const int n = nbase + nr;
    const int c = min(cnt[n], CAP);
    const int rpn = rp[n];

    int sv = n;
    if (lane < c) sv = colc[rpn + lane];
    const float dvw = rsqrtf((float)cnt[sv] + 1.0f);
    const float dv  = (lane <= c) ? dvw : 0.0f;

    const _Float16* hbase = H + lane * 2;
    const int ned4 = (c + 1 + 3) & ~3;

    f16x2 va[4]; float wa[4];
#pragma unroll
    for (int t = 0; t < 4; ++t) {
        const int   e = min(t, 63);
        const int   s = __shfl(sv, e);
        wa[t]         = __shfl(dv, e);
        va[t] = *(const f16x2*)&hbase[(size_t)s * 128];
    }
    float ax = 0.f, ay = 0.f;
    for (int j = 4; j < ned4; j += 4) {
        f16x2 vb[4]; float wb[4];
#pragma unroll
        for (int t = 0; t < 4; ++t) {
            const int   e = min(j + t, 63);
            const int   s = __shfl(sv, e);
            wb[t]         = __shfl(dv, e);
            vb[t] = *(const f16x2*)&hbase[(size_t)s * 128];
        }
#pragma unroll
        for (int t = 0; t < 4; ++t) {
            ax = fmaf(wa[t], (float)va[t][0], ax);
            ay = fmaf(wa[t], (float)va[t][1], ay);
            va[t] = vb[t]; wa[t] = wb[t];
        }
    }
#pragma unroll
    for (int t = 0; t < 4; ++t) {
        ax = fmaf(wa[t], (float)va[t][0], ax);
        ay = fmaf(wa[t], (float)va[t][1], ay);
    }

    const float dn = __shfl(dv, c);         // dinv[n]
    const float2 b = *(const float2*)&b1[lane * 2];
    const float hr0 = fmaxf(ax * dn + b.x, 0.f);
    const float hr1 = fmaxf(ay * dn + b.y, 0.f);

    const float4 wa0 = *(const float4*)&W2[(size_t)(lane * 2) * 8];
    const float4 wa1 = *(const float4*)&W2[(size_t)(lane * 2) * 8 + 4];
    const float4 wb0 = *(const float4*)&W2[(size_t)(lane * 2 + 1) * 8];
    const float4 wb1 = *(const float4*)&W2[(size_t)(lane * 2 + 1) * 8 + 4];
    float p[8];
    p[0] = hr0 * wa0.x + hr1 * wb0.x;
    p[1] = hr0 * wa0.y + hr1 * wb0.y;
    p[2] = hr0 * wa0.z + hr1 * wb0.z;
    p[3] = hr0 * wa0.w + hr1 * wb0.w;
    p[4] = hr0 * wa1.x + hr1 * wb1.x;
    p[5] = hr0 * wa1.y + hr1 * wb1.y;
    p[6] = hr0 * wa1.z + hr1 * wb1.z;
    p[7] = hr0 * wa1.w + hr1 * wb1.w;
#pragma unroll
    for (int off = 32; off > 0; off >>= 1)
#pragma unroll
        for (int j = 0; j < 8; ++j) p[j] += __shfl_xor(p[j], off);
    if (lane == 0) {
        *(float4*)&Z[(size_t)n * 8]     = make_float4(p[0], p[1], p[2], p[3]);
        *(float4*)&Z[(size_t)n * 8 + 4] = make_float4(p[4], p[5], p[6], p[7]);
    }
}

// ---------------------------------------------------------------- Aggregation layer 2 (F=8)
__global__ __launch_bounds__(64) void agg2(const float* __restrict__ Z,
                                           const int* __restrict__ cnt,
                                           const int* __restrict__ rp,
                                           const int* __restrict__ colc,
                                           const float* __restrict__ b2,
                                           float* __restrict__ ZA) {
    const int n = blockIdx.x * blockDim.x + threadIdx.x;
    if (n >= N) return;
    const int c = min(cnt[n], CAP);
    const int rpn = rp[n];
    float acc[8] = {};

    float4 va0[4], va1[4]; float wv[4];
#pragma unroll
    for (int t = 0; t < 4; ++t) {
        const int s = (t < c) ? colc[rpn + t] : n;
        wv[t]  = (t < c) ? rsqrtf((float)cnt[s] + 1.0f) : 0.0f;
        va0[t] = *(const float4*)&Z[(size_t)s * 8];
        va1[t] = *(const float4*)&Z[(size_t)s * 8 + 4];
    }
    for (int j = 4; j + 4 <= c + 4; j += 4) {
        float4 vb0[4], vb1[4]; float wb[4];
#pragma unroll
        for (int t = 0; t < 4; ++t) {
            const int jt = j + t;
            const int s  = (jt < c) ? colc[rpn + jt] : n;
            wb[t]  = (jt < c) ? rsqrtf((float)cnt[s] + 1.0f) : 0.0f;
            vb0[t] = *(const float4*)&Z[(size_t)s * 8];
            vb1[t] = *(const float4*)&Z[(size_t)s * 8 + 4];
        }
#pragma unroll
        for (int t = 0; t < 4; ++t) {
            const float w = wv[t];
            acc[0] = fmaf(w, va0[t].x, acc[0]); acc[1] = fmaf(w, va0[t].y, acc[1]);
            acc[2] = fmaf(w, va0[t].z, acc[2]); acc[3] = fmaf(w, va0[t].w, acc[3]);
            acc[4] = fmaf(w, va1[t].x, acc[4]); acc[5] = fmaf(w, va1[t].y, acc[5]);
            acc[6] = fmaf(w, va1[t].z, acc[6]); acc[7] = fmaf(w, va1[t].w, acc[7]);
            va0[t] = vb0[t]; va1[t] = vb1[t]; wv[t] = wb[t];
        }
    }
#pragma unroll
    for (int t = 0; t < 4; ++t) {
        const float w = wv[t];
        acc[0] = fmaf(w, va0[t].x, acc[0]); acc[1] = fmaf(w, va0[t].y, acc[1]);
        acc[2] = fmaf(w, va0[t].z, acc[2]); acc[3] = fmaf(w, va0[t].w, acc[3]);
        acc[4] = fmaf(w, va1[t].x, acc[4]); acc[5] = fmaf(w, va1[t].y, acc[5]);
        acc[6] = fmaf(w, va1[t].z, acc[6]); acc[7] = fmaf(w, va1[t].w, acc[7]);
    }

    const float dn = rsqrtf((float)c + 1.0f);
    const float4 zn0 = *(const float4*)&Z[(size_t)n * 8];
    const float4 zn1 = *(const float4*)&Z[(size_t)n * 8 + 4];
    float o[8];
    o[0] = (acc[0] + dn * zn0.x) * dn + b2[0];
    o[1] = (acc[1] + dn * zn0.y) * dn + b2[1];
    o[2] = (acc[2] + dn * zn0.z) * dn + b2[2];
    o[3] = (acc[3] + dn * zn0.w) * dn + b2[3];
    o[4] = (acc[4] + dn * zn1.x) * dn + b2[4];
    o[5] = (acc[5] + dn * zn1.y) * dn + b2[5];
    o[6] = (acc[6] + dn * zn1.z) * dn + b2[6];
    o[7] = (acc[7] + dn * zn1.w) * dn + b2[7];
    *(float4*)&ZA[(size_t)n * 8]     = make_float4(o[0], o[1], o[2], o[3]);
    *(float4*)&ZA[(size_t)n * 8 + 4] = make_float4(o[4], o[5], o[6], o[7]);
}

// ---------------------------------------------------------------- Edge scoring
__global__ __launch_bounds__(256) void score(const float* __restrict__ ZA,
                                             const int* __restrict__ pe,
                                             const int* __restrict__ ne,
                                             float* __restrict__ out) {
    const int e = blockIdx.x * blockDim.x + threadIdx.x;
    if (e >= ES) return;
    int a, b;
    if (e < EP) { a = pe[e];      b = pe[EP + e]; }
    else        { a = ne[e - EP]; b = ne[e];      }
    const float4 xa0 = *(const float4*)&ZA[(size_t)a * 8];
    const float4 xa1 = *(const float4*)&ZA[(size_t)a * 8 + 4];
    const float4 xb0 = *(const float4*)&ZA[(size_t)b * 8];
    const float4 xb1 = *(const float4*)&ZA[(size_t)b * 8 + 4];
    out[e] = xa0.x * xb0.x + xa0.y * xb0.y + xa0.z * xb0.z + xa0.w * xb0.w +
             xa1.x * xb1.x + xa1.y * xb1.y + xa1.z * xb1.z + xa1.w * xb1.w;
}

// ---------------------------------------------------------------- launch

extern "C" void kernel_launch(void* const* d_in, const int* in_sizes, int n_in,
                              void* d_out, int out_size, void* d_ws, size_t ws_size,
                              hipStream_t stream) {
    const float* x  = (const float*)d_in[0];
    const int*   ei = (const int*)d_in[1];   // [2, 1.6M] row-major
    const int*   pe = (const int*)d_in[2];   // [2, 200k]
    const int*   ne = (const int*)d_in[3];   // [2, 200k]
    const float* W1 = (const float*)d_in[4];
    const float* b1 = (const float*)d_in[5];
    const float* W2 = (const float*)d_in[6];
    const float* b2 = (const float*)d_in[7];
    float* out = (float*)d_out;

    char* ws = (char*)d_ws;
    size_t off = 0;
    auto carve = [&](size_t bytes) {
        char* p = ws + off;
        off += (bytes + 255) & ~(size_t)255;
        return p;
    };
    int*       gcnt = (int*)      carve((size_t)XG2 * sizeof(int));          // 512 B
    int*       cnt  = (int*)      carve((size_t)N * sizeof(int));            // 0.4 MB (fully written by fill_csr)
    int*       rp   = (int*)      carve((size_t)N * sizeof(int));            // 0.4 MB
    unsigned*  eb   = (unsigned*) carve((size_t)XG2 * SEGCAP * sizeof(unsigned)); // 7.0 MB
    int*       colc = (int*)      carve((size_t)XG2 * SEGCAP * sizeof(int)); // 7.0 MB (CSR col)
    _Float16*  H    = (_Float16*) carve((size_t)N * 128 * sizeof(_Float16)); // 25.6 MB
    float*     Z    = (float*)    carve((size_t)N * 8 * sizeof(float));      // 3.2 MB
    float*     ZA   = (float*)    carve((size_t)N * 8 * sizeof(float));      // 3.2 MB
    _Float16*  W1T  = (_Float16*) carve((size_t)128 * 256 * sizeof(_Float16)); // 64 KB

    hipMemsetAsync(gcnt, 0, (size_t)XG2 * sizeof(int), stream);
    partition_edges<<<NPB, PBS, 0, stream>>>(ei, gcnt, eb);
    w1_transpose   <<<128, 256, 0, stream>>>(W1, W1T);
    fill_csr       <<<XG2, 1024, 0, stream>>>(eb, gcnt, cnt, rp, colc);
    gemm1_mfma     <<<(N + 255) / 256, 256, 0, stream>>>(x, W1T, H);
    agg1_gemm2     <<<(NH * 64 + 255) / 256, 256, 0, stream>>>(H, cnt, rp, colc, b1, W2, Z, 0, NH);
    agg1_gemm2     <<<((N - NH) * 64 + 255) / 256, 256, 0, stream>>>(H, cnt, rp, colc, b1, W2, Z, NH, N - NH);
    agg2           <<<(N + 63) / 64, 64, 0, stream>>>(Z, cnt, rp, colc, b2, ZA);
    score          <<<(ES + 255) / 256, 256, 0, stream>>>(ZA, pe, ne, out);
}

// Round 8
// 357.393 us; speedup vs baseline: 1.2371x; 1.0044x over previous
//
#include <hip/hip_runtime.h>

constexpr int N   = 100000;   // nodes
constexpr int E   = 1600000;  // message edges
constexpr int EP  = 200000;   // pos scored edges
constexpr int ES  = 400000;   // total scored edges (pos+neg)
constexpr int CAP = 64;       // per-node fan-in clamp for lane-gather (Poisson(16): P(deg>64)~1e-18)
constexpr int XG2 = 128;      // radix groups (round-19: CSR counting-sort fill)
constexpr int DR2 = (N + XG2 - 1) / XG2;    // 782 nodes per group
constexpr int SEGCAP = 14336; // per-group segment capacity (E/128=12500 mean, +16 sigma)
constexpr int EPB = 8192;     // edges per partition block
constexpr int PBS = 1024;     // partition block size
constexpr int NPB = (E + EPB - 1) / EPB;    // 196 partition blocks
constexpr int BSTR = 264;     // gemm1 LDS B k-stride (f16): 264*2B=528B -> bank (4n+4q)%32, 2-way max

typedef _Float16 f16x8 __attribute__((ext_vector_type(8)));
typedef _Float16 f16x4 __attribute__((ext_vector_type(4)));
typedef _Float16 f16x2 __attribute__((ext_vector_type(2)));
typedef float    f32x4 __attribute__((ext_vector_type(4)));

// ---------------------------------------------------------------- Pass A: partition edges
// 196 blocks x 8192 edges, LDS histogram + ONE global atomic per group per
// block. 128 groups; pack = rel(10b)<<17 | src(17b).
__global__ __launch_bounds__(1024) void partition_edges(const int* __restrict__ ei,
                                                        int* __restrict__ gcnt,
                                                        unsigned* __restrict__ eb) {
    __shared__ int lh[XG2];   // block histogram
    __shared__ int rk[XG2];   // running rank counters (init = global base)
    const int tid = threadIdx.x;
    const int e0  = blockIdx.x * EPB;
    if (tid < XG2) lh[tid] = 0;
    __syncthreads();
#pragma unroll
    for (int i = 0; i < EPB; i += PBS) {
        const int e = e0 + i + tid;
        if (e < E) {
            const int d = ei[E + e];
            atomicAdd(&lh[d / DR2], 1);
        }
    }
    __syncthreads();
    if (tid < XG2) rk[tid] = atomicAdd(&gcnt[tid], lh[tid]);  // one hot atomic per group per block
    __syncthreads();
#pragma unroll
    for (int i = 0; i < EPB; i += PBS) {
        const int e = e0 + i + tid;
        if (e < E) {
            const int s   = ei[e];
            const int d   = ei[E + e];
            const int g   = d / DR2;
            const int rel = d - g * DR2;               // < 782 < 2^10
            const int p   = atomicAdd(&rk[g], 1);
            if (p < SEGCAP)
                eb[(size_t)g * SEGCAP + p] = ((unsigned)rel << 17) | (unsigned)s;
        }
    }
}

// ---------------------------------------------------------------- Pass B: CSR counting sort
// Rounds 16/18 proved 4B scattered col stores CANNOT be L2-merged (WRITE
// 63/52MB for 6.4MB payload). One 1024-thread block per group finishes the
// sort in LDS, writes everything coalesced. Round-19: 442 -> 359us total.
__global__ __launch_bounds__(1024) void fill_csr(const unsigned* __restrict__ eb,
                                                 const int* __restrict__ gcnt,
                                                 int* __restrict__ cnt,
                                                 int* __restrict__ rp,
                                                 int* __restrict__ colc) {
    __shared__ int hcnt[1024];          // counts -> cursors (DR2=782 used)
    __shared__ int wsum[16];
    __shared__ unsigned stage[SEGCAP];  // 57.3 KB
    const int g   = blockIdx.x;
    const int tid = threadIdx.x;
    const int cg  = min(gcnt[g], SEGCAP);
    const unsigned* seg = eb + (size_t)g * SEGCAP;

    hcnt[tid] = 0;
    __syncthreads();
    for (int i = tid; i < cg; i += 1024)
        atomicAdd(&hcnt[seg[i] >> 17], 1);
    __syncthreads();

    // exclusive scan over 1024 counters (wave scan + wave-sum scan)
    const int c    = hcnt[tid];
    const int lane = tid & 63;
    const int wid  = tid >> 6;
    int incl = c;
#pragma unroll
    for (int off = 1; off < 64; off <<= 1) {
        const int v = __shfl_up(incl, off);
        if (lane >= off) incl += v;
    }
    if (lane == 63) wsum[wid] = incl;
    __syncthreads();
    if (tid < 16) {
        int v = wsum[tid];
#pragma unroll
        for (int off = 1; off < 16; off <<= 1) {
            const int u = __shfl_up(v, off);
            if (tid >= off) v += u;
        }
        wsum[tid] = v;   // inclusive wave sums
    }
    __syncthreads();
    const int excl = incl - c + (wid ? wsum[wid - 1] : 0);

    const int base = g * DR2;
    if (tid < DR2 && base + tid < N) {
        cnt[base + tid] = c;                       // full in-degree
        rp [base + tid] = g * SEGCAP + excl;       // CSR row start
    }
    __syncthreads();       // scan reads done before cursor overwrite
    hcnt[tid] = excl;
    __syncthreads();

    for (int i = tid; i < cg; i += 1024) {
        const unsigned pk = seg[i];
        const int p = atomicAdd(&hcnt[pk >> 17], 1);
        stage[p] = pk & 0x1FFFFu;
    }
    __syncthreads();
    for (int i = tid; i < cg; i += 1024)
        colc[(size_t)g * SEGCAP + i] = (int)stage[i];   // full-line streaming writes
}

// ---------------------------------------------------------------- W1 transpose prep
__global__ __launch_bounds__(256) void w1_transpose(const float* __restrict__ W1,
                                                    _Float16* __restrict__ W1T) {
    const int n = blockIdx.x;          // 0..127
    const int k = threadIdx.x;         // 0..255
    W1T[n * 256 + k] = (_Float16)W1[(size_t)k * 128 + n];
}

// ---------------------------------------------------------------- GEMM1 (f16 MFMA)
// B-stationary, ZERO barriers in K-loop; whole W1T in padded LDS; A streams
// global->reg->f16 nontemporal; M_rep=4 -> 32 MFMA per 8 ds_read_b128 +
// 8 global dwordx4 per k-step.
__global__ __launch_bounds__(256) void gemm1_mfma(const float* __restrict__ X,
                                                  const _Float16* __restrict__ W1T,
                                                  _Float16* __restrict__ H) {
    __shared__ _Float16 Bs[128][BSTR];   // 67.6 KB -> 2 blocks/CU

    const int tid  = threadIdx.x;
    const int wave = tid >> 6;
    const int lane = tid & 63;
    const int m16  = lane & 15;
    const int quad = lane >> 4;
    const int rowBase = blockIdx.x * 256 + wave * 64;

    // ---- preload whole W1T into LDS (16 x b128 per thread), once
#pragma unroll
    for (int i = 0; i < 16; ++i) {
        const int c  = tid + 256 * i;         // 4096 chunks of 16B
        const int n  = c >> 5;                // row (col of W1)
        const int kb = (c & 31) * 16;         // byte within row
        *(f16x8*)((char*)&Bs[n][0] + kb) = *(const f16x8*)((const char*)W1T + (size_t)c * 16);
    }
    __syncthreads();   // the only barrier in the kernel

    f32x4 acc[4][8] = {};
    f32x4 avA[8];

    auto loadA = [&](int k0) {
#pragma unroll
        for (int m = 0; m < 4; ++m) {
            int gr = rowBase + m * 16 + m16;
            gr = gr < N ? gr : N - 1;         // clamp (stores guarded)
            const f32x4* p = (const f32x4*)&X[(size_t)gr * 256 + k0 + quad * 8];
            avA[2 * m]     = __builtin_nontemporal_load(p);
            avA[2 * m + 1] = __builtin_nontemporal_load(p + 1);
        }
    };

    loadA(0);
    for (int k0 = 0; k0 < 256; k0 += 32) {
        f16x8 af[4];
#pragma unroll
        for (int m = 0; m < 4; ++m) {
            f16x8 h;
            h[0] = (_Float16)avA[2*m][0];   h[1] = (_Float16)avA[2*m][1];
            h[2] = (_Float16)avA[2*m][2];   h[3] = (_Float16)avA[2*m][3];
            h[4] = (_Float16)avA[2*m+1][0]; h[5] = (_Float16)avA[2*m+1][1];
            h[6] = (_Float16)avA[2*m+1][2]; h[7] = (_Float16)avA[2*m+1][3];
            af[m] = h;
        }
        if (k0 + 32 < 256) loadA(k0 + 32);    // prefetch next tile into regs
#pragma unroll
        for (int nt = 0; nt < 8; ++nt) {
            const f16x8 bf = *(const f16x8*)&Bs[nt * 16 + m16][k0 + quad * 8];
#pragma unroll
            for (int m = 0; m < 4; ++m)
                acc[m][nt] = __builtin_amdgcn_mfma_f32_16x16x32_f16(af[m], bf, acc[m][nt], 0, 0, 0);
        }
    }

    // ---- epilogue: C/D layout col=lane&15, row=quad*4+r (verified convention)
#pragma unroll
    for (int m = 0; m < 4; ++m)
#pragma unroll
        for (int nt = 0; nt < 8; ++nt)
#pragma unroll
            for (int r = 0; r < 4; ++r) {
                const int gm = rowBase + m * 16 + quad * 4 + r;
                if (gm < N) H[(size_t)gm * 128 + nt * 16 + m16] = (_Float16)acc[m][nt][r];
            }
}

// ---------------------------------------------------------------- Fused agg1 + gemm2
// One wave per node; lane l owns feats [2l, 2l+1]; depth-4 prefetch.
// Round-20: SINGLE full-range launch (was 2 halves) — at ~110-130us it will
// out-rank the harness's 60us workspace-poison fill in the profile and give
// us its first real counters (FETCH discriminates L3-absorbed vs thrashing).
__global__ __launch_bounds__(256) void agg1_gemm2(const _Float16* __restrict__ H,
                                                  const int* __restrict__ cnt,
                                                  const int* __restrict__ rp,
                                                  const int* __restrict__ colc,
                                                  const float* __restrict__ b1,
                                                  const float* __restrict__ W2,
                                                  float* __restrict__ Z) {
    const int n    = (blockIdx.x * blockDim.x + threadIdx.x) >> 6;
    const int lane = threadIdx.x & 63;
    if (n >= N) return;
    const int c = min(cnt[n], CAP);
    const int rpn = rp[n];

    int sv = n;
    if (lane < c) sv = colc[rpn + lane];
    const float dvw = rsqrtf((float)cnt[sv] + 1.0f);
    const float dv  = (lane <= c) ? dvw : 0.0f;

    const _Float16* hbase = H + lane * 2;
    const int ned4 = (c + 1 + 3) & ~3;

    f16x2 va[4]; float wa[4];
#pragma unroll
    for (int t = 0; t < 4; ++t) {
        const int   e = min(t, 63);
        const int   s = __shfl(sv, e);
        wa[t]         = __shfl(dv, e);
        va[t] = *(const f16x2*)&hbase[(size_t)s * 128];
    }
    float ax = 0.f, ay = 0.f;
    for (int j = 4; j < ned4; j += 4) {
        f16x2 vb[4]; float wb[4];
#pragma unroll
        for (int t = 0; t < 4; ++t) {
            const int   e = min(j + t, 63);
            const int   s = __shfl(sv, e);
            wb[t]         = __shfl(dv, e);
            vb[t] = *(const f16x2*)&hbase[(size_t)s * 128];
        }
#pragma unroll
        for (int t = 0; t < 4; ++t) {
            ax = fmaf(wa[t], (float)va[t][0], ax);
            ay = fmaf(wa[t], (float)va[t][1], ay);
            va[t] = vb[t]; wa[t] = wb[t];
        }
    }
#pragma unroll
    for (int t = 0; t < 4; ++t) {
        ax = fmaf(wa[t], (float)va[t][0], ax);
        ay = fmaf(wa[t], (float)va[t][1], ay);
    }

    const float dn = __shfl(dv, c);         // dinv[n]
    const float2 b = *(const float2*)&b1[lane * 2];
    const float hr0 = fmaxf(ax * dn + b.x, 0.f);
    const float hr1 = fmaxf(ay * dn + b.y, 0.f);

    const float4 wa0 = *(const float4*)&W2[(size_t)(lane * 2) * 8];
    const float4 wa1 = *(const float4*)&W2[(size_t)(lane * 2) * 8 + 4];
    const float4 wb0 = *(const float4*)&W2[(size_t)(lane * 2 + 1) * 8];
    const float4 wb1 = *(const float4*)&W2[(size_t)(lane * 2 + 1) * 8 + 4];
    float p[8];
    p[0] = hr0 * wa0.x + hr1 * wb0.x;
    p[1] = hr0 * wa0.y + hr1 * wb0.y;
    p[2] = hr0 * wa0.z + hr1 * wb0.z;
    p[3] = hr0 * wa0.w + hr1 * wb0.w;
    p[4] = hr0 * wa1.x + hr1 * wb1.x;
    p[5] = hr0 * wa1.y + hr1 * wb1.y;
    p[6] = hr0 * wa1.z + hr1 * wb1.z;
    p[7] = hr0 * wa1.w + hr1 * wb1.w;
#pragma unroll
    for (int off = 32; off > 0; off >>= 1)
#pragma unroll
        for (int j = 0; j < 8; ++j) p[j] += __shfl_xor(p[j], off);
    if (lane == 0) {
        *(float4*)&Z[(size_t)n * 8]     = make_float4(p[0], p[1], p[2], p[3]);
        *(float4*)&Z[(size_t)n * 8 + 4] = make_float4(p[4], p[5], p[6], p[7]);
    }
}

// ---------------------------------------------------------------- Aggregation layer 2 (F=8)
// Round-20: was 1 thread/node -> only 1563 waves (0.8/SIMD) serially walking
// ~16 L2-hit gathers each: latency-bound. Now 8 lanes per node (lane=feat):
// 12.5K waves (8x TLP), Z-row read = one coalesced 32B request per octet,
// colc/cnt loads are same-address broadcasts within the octet.
__global__ __launch_bounds__(256) void agg2(const float* __restrict__ Z,
                                            const int* __restrict__ cnt,
                                            const int* __restrict__ rp,
                                            const int* __restrict__ colc,
                                            const float* __restrict__ b2,
                                            float* __restrict__ ZA) {
    const int t = blockIdx.x * blockDim.x + threadIdx.x;
    const int n = t >> 3;              // node
    const int f = t & 7;               // feature
    if (n >= N) return;
    const int c   = min(cnt[n], CAP);
    const int rpn = rp[n];

    float acc = 0.f;
    float zv[4], wv[4];
#pragma unroll
    for (int tt = 0; tt < 4; ++tt) {
        const int s = (tt < c) ? colc[rpn + tt] : n;
        wv[tt] = (tt < c) ? rsqrtf((float)cnt[s] + 1.0f) : 0.0f;
        zv[tt] = Z[(size_t)s * 8 + f];
    }
    for (int j = 4; j + 4 <= c + 4; j += 4) {
        float zb[4], wb[4];
#pragma unroll
        for (int tt = 0; tt < 4; ++tt) {
            const int jt = j + tt;
            const int s  = (jt < c) ? colc[rpn + jt] : n;
            wb[tt] = (jt < c) ? rsqrtf((float)cnt[s] + 1.0f) : 0.0f;
            zb[tt] = Z[(size_t)s * 8 + f];
        }
#pragma unroll
        for (int tt = 0; tt < 4; ++tt) {
            acc = fmaf(wv[tt], zv[tt], acc);
            zv[tt] = zb[tt]; wv[tt] = wb[tt];
        }
    }
#pragma unroll
    for (int tt = 0; tt < 4; ++tt) acc = fmaf(wv[tt], zv[tt], acc);

    const float dn = rsqrtf((float)c + 1.0f);
    const float zn = Z[(size_t)n * 8 + f];
    ZA[(size_t)n * 8 + f] = (acc + dn * zn) * dn + b2[f];
}

// ---------------------------------------------------------------- Edge scoring
__global__ __launch_bounds__(256) void score(const float* __restrict__ ZA,
                                             const int* __restrict__ pe,
                                             const int* __restrict__ ne,
                                             float* __restrict__ out) {
    const int e = blockIdx.x * blockDim.x + threadIdx.x;
    if (e >= ES) return;
    int a, b;
    if (e < EP) { a = pe[e];      b = pe[EP + e]; }
    else        { a = ne[e - EP]; b = ne[e];      }
    const float4 xa0 = *(const float4*)&ZA[(size_t)a * 8];
    const float4 xa1 = *(const float4*)&ZA[(size_t)a * 8 + 4];
    const float4 xb0 = *(const float4*)&ZA[(size_t)b * 8];
    const float4 xb1 = *(const float4*)&ZA[(size_t)b * 8 + 4];
    out[e] = xa0.x * xb0.x + xa0.y * xb0.y + xa0.z * xb0.z + xa0.w * xb0.w +
             xa1.x * xb1.x + xa1.y * xb1.y + xa1.z * xb1.z + xa1.w * xb1.w;
}

// ---------------------------------------------------------------- launch

extern "C" void kernel_launch(void* const* d_in, const int* in_sizes, int n_in,
                              void* d_out, int out_size, void* d_ws, size_t ws_size,
                              hipStream_t stream) {
    const float* x  = (const float*)d_in[0];
    const int*   ei = (const int*)d_in[1];   // [2, 1.6M] row-major
    const int*   pe = (const int*)d_in[2];   // [2, 200k]
    const int*   ne = (const int*)d_in[3];   // [2, 200k]
    const float* W1 = (const float*)d_in[4];
    const float* b1 = (const float*)d_in[5];
    const float* W2 = (const float*)d_in[6];
    const float* b2 = (const float*)d_in[7];
    float* out = (float*)d_out;

    char* ws = (char*)d_ws;
    size_t off = 0;
    auto carve = [&](size_t bytes) {
        char* p = ws + off;
        off += (bytes + 255) & ~(size_t)255;
        return p;
    };
    int*       gcnt = (int*)      carve((size_t)XG2 * sizeof(int));          // 512 B
    int*       cnt  = (int*)      carve((size_t)N * sizeof(int));            // 0.4 MB (fully written by fill_csr)
    int*       rp   = (int*)      carve((size_t)N * sizeof(int));            // 0.4 MB
    unsigned*  eb   = (unsigned*) carve((size_t)XG2 * SEGCAP * sizeof(unsigned)); // 7.0 MB
    int*       colc = (int*)      carve((size_t)XG2 * SEGCAP * sizeof(int)); // 7.0 MB (CSR col)
    _Float16*  H    = (_Float16*) carve((size_t)N * 128 * sizeof(_Float16)); // 25.6 MB
    float*     Z    = (float*)    carve((size_t)N * 8 * sizeof(float));      // 3.2 MB
    float*     ZA   = (float*)    carve((size_t)N * 8 * sizeof(float));      // 3.2 MB
    _Float16*  W1T  = (_Float16*) carve((size_t)128 * 256 * sizeof(_Float16)); // 64 KB

    hipMemsetAsync(gcnt, 0, (size_t)XG2 * sizeof(int), stream);
    partition_edges<<<NPB, PBS, 0, stream>>>(ei, gcnt, eb);
    w1_transpose   <<<128, 256, 0, stream>>>(W1, W1T);
    fill_csr       <<<XG2, 1024, 0, stream>>>(eb, gcnt, cnt, rp, colc);
    gemm1_mfma     <<<(N + 255) / 256, 256, 0, stream>>>(x, W1T, H);
    agg1_gemm2     <<<((size_t)N * 64 + 255) / 256, 256, 0, stream>>>(H, cnt, rp, colc, b1, W2, Z);
    agg2           <<<((size_t)N * 8 + 255) / 256, 256, 0, stream>>>(Z, cnt, rp, colc, b2, ZA);
    score          <<<(ES + 255) / 256, 256, 0, stream>>>(ZA, pe, ne, out);
}

// Round 9
// 348.735 us; speedup vs baseline: 1.2679x; 1.0248x over previous
//
#include <hip/hip_runtime.h>

constexpr int N   = 100000;   // nodes
constexpr int E   = 1600000;  // message edges
constexpr int EP  = 200000;   // pos scored edges
constexpr int ES  = 400000;   // total scored edges (pos+neg)
constexpr int CAP = 64;       // per-node fan-in clamp for lane-gather (Poisson(16): P(deg>64)~1e-18)
constexpr int XG2 = 128;      // radix groups (CSR counting-sort fill)
constexpr int DR2 = (N + XG2 - 1) / XG2;    // 782 nodes per group
constexpr int SEGCAP = 14336; // per-group segment capacity (E/128=12500 mean, +16 sigma)
constexpr int EPB = 8192;     // edges per partition block
constexpr int PBS = 1024;     // partition block size
constexpr int NPB = (E + EPB - 1) / EPB;    // 196 partition blocks
constexpr int BSTR = 264;     // gemm1 LDS B k-stride (f16): 264*2B=528B -> bank (4n+4q)%32, 2-way max

typedef _Float16 f16x8 __attribute__((ext_vector_type(8)));
typedef _Float16 f16x4 __attribute__((ext_vector_type(4)));
typedef _Float16 f16x2 __attribute__((ext_vector_type(2)));
typedef float    f32x4 __attribute__((ext_vector_type(4)));

// ---------------------------------------------------------------- Pass A: partition edges
// 196 blocks x 8192 edges, LDS histogram + ONE global atomic per group per
// block. 128 groups; pack = rel(10b)<<17 | src(17b).
__global__ __launch_bounds__(1024) void partition_edges(const int* __restrict__ ei,
                                                        int* __restrict__ gcnt,
                                                        unsigned* __restrict__ eb) {
    __shared__ int lh[XG2];   // block histogram
    __shared__ int rk[XG2];   // running rank counters (init = global base)
    const int tid = threadIdx.x;
    const int e0  = blockIdx.x * EPB;
    if (tid < XG2) lh[tid] = 0;
    __syncthreads();
#pragma unroll
    for (int i = 0; i < EPB; i += PBS) {
        const int e = e0 + i + tid;
        if (e < E) {
            const int d = ei[E + e];
            atomicAdd(&lh[d / DR2], 1);
        }
    }
    __syncthreads();
    if (tid < XG2) rk[tid] = atomicAdd(&gcnt[tid], lh[tid]);  // one hot atomic per group per block
    __syncthreads();
#pragma unroll
    for (int i = 0; i < EPB; i += PBS) {
        const int e = e0 + i + tid;
        if (e < E) {
            const int s   = ei[e];
            const int d   = ei[E + e];
            const int g   = d / DR2;
            const int rel = d - g * DR2;               // < 782 < 2^10
            const int p   = atomicAdd(&rk[g], 1);
            if (p < SEGCAP)
                eb[(size_t)g * SEGCAP + p] = ((unsigned)rel << 17) | (unsigned)s;
        }
    }
}

// ---------------------------------------------------------------- Pass B: CSR counting sort
// 4B scattered col stores cannot be L2-merged (rounds 16/18); one 1024-thread
// block per group finishes the sort in LDS, writes everything coalesced.
// Round-21: also emits dinv[n] = rsqrt(deg+1) (free — c is in hand) so the
// aggregation kernels never gather cnt again.
__global__ __launch_bounds__(1024) void fill_csr(const unsigned* __restrict__ eb,
                                                 const int* __restrict__ gcnt,
                                                 int* __restrict__ cnt,
                                                 int* __restrict__ rp,
                                                 float* __restrict__ dinv,
                                                 int* __restrict__ colc) {
    __shared__ int hcnt[1024];          // counts -> cursors (DR2=782 used)
    __shared__ int wsum[16];
    __shared__ unsigned stage[SEGCAP];  // 57.3 KB
    const int g   = blockIdx.x;
    const int tid = threadIdx.x;
    const int cg  = min(gcnt[g], SEGCAP);
    const unsigned* seg = eb + (size_t)g * SEGCAP;

    hcnt[tid] = 0;
    __syncthreads();
    for (int i = tid; i < cg; i += 1024)
        atomicAdd(&hcnt[seg[i] >> 17], 1);
    __syncthreads();

    // exclusive scan over 1024 counters (wave scan + wave-sum scan)
    const int c    = hcnt[tid];
    const int lane = tid & 63;
    const int wid  = tid >> 6;
    int incl = c;
#pragma unroll
    for (int off = 1; off < 64; off <<= 1) {
        const int v = __shfl_up(incl, off);
        if (lane >= off) incl += v;
    }
    if (lane == 63) wsum[wid] = incl;
    __syncthreads();
    if (tid < 16) {
        int v = wsum[tid];
#pragma unroll
        for (int off = 1; off < 16; off <<= 1) {
            const int u = __shfl_up(v, off);
            if (tid >= off) v += u;
        }
        wsum[tid] = v;   // inclusive wave sums
    }
    __syncthreads();
    const int excl = incl - c + (wid ? wsum[wid - 1] : 0);

    const int base = g * DR2;
    if (tid < DR2 && base + tid < N) {
        cnt [base + tid] = c;                      // full in-degree
        rp  [base + tid] = g * SEGCAP + excl;      // CSR row start
        dinv[base + tid] = rsqrtf((float)c + 1.0f);
    }
    __syncthreads();       // scan reads done before cursor overwrite
    hcnt[tid] = excl;
    __syncthreads();

    for (int i = tid; i < cg; i += 1024) {
        const unsigned pk = seg[i];
        const int p = atomicAdd(&hcnt[pk >> 17], 1);
        stage[p] = pk & 0x1FFFFu;
    }
    __syncthreads();
    for (int i = tid; i < cg; i += 1024)
        colc[(size_t)g * SEGCAP + i] = (int)stage[i];   // full-line streaming writes
}

// ---------------------------------------------------------------- W1 transpose prep
__global__ __launch_bounds__(256) void w1_transpose(const float* __restrict__ W1,
                                                    _Float16* __restrict__ W1T) {
    const int n = blockIdx.x;          // 0..127
    const int k = threadIdx.x;         // 0..255
    W1T[n * 256 + k] = (_Float16)W1[(size_t)k * 128 + n];
}

// ---------------------------------------------------------------- GEMM1 (f16 MFMA)
// B-stationary, ZERO barriers in K-loop; whole W1T in padded LDS; A streams
// global->reg->f16 nontemporal; M_rep=4 -> 32 MFMA per 8 ds_read_b128 +
// 8 global dwordx4 per k-step.
__global__ __launch_bounds__(256) void gemm1_mfma(const float* __restrict__ X,
                                                  const _Float16* __restrict__ W1T,
                                                  _Float16* __restrict__ H) {
    __shared__ _Float16 Bs[128][BSTR];   // 67.6 KB -> 2 blocks/CU

    const int tid  = threadIdx.x;
    const int wave = tid >> 6;
    const int lane = tid & 63;
    const int m16  = lane & 15;
    const int quad = lane >> 4;
    const int rowBase = blockIdx.x * 256 + wave * 64;

    // ---- preload whole W1T into LDS (16 x b128 per thread), once
#pragma unroll
    for (int i = 0; i < 16; ++i) {
        const int c  = tid + 256 * i;         // 4096 chunks of 16B
        const int n  = c >> 5;                // row (col of W1)
        const int kb = (c & 31) * 16;         // byte within row
        *(f16x8*)((char*)&Bs[n][0] + kb) = *(const f16x8*)((const char*)W1T + (size_t)c * 16);
    }
    __syncthreads();   // the only barrier in the kernel

    f32x4 acc[4][8] = {};
    f32x4 avA[8];

    auto loadA = [&](int k0) {
#pragma unroll
        for (int m = 0; m < 4; ++m) {
            int gr = rowBase + m * 16 + m16;
            gr = gr < N ? gr : N - 1;         // clamp (stores guarded)
            const f32x4* p = (const f32x4*)&X[(size_t)gr * 256 + k0 + quad * 8];
            avA[2 * m]     = __builtin_nontemporal_load(p);
            avA[2 * m + 1] = __builtin_nontemporal_load(p + 1);
        }
    };

    loadA(0);
    for (int k0 = 0; k0 < 256; k0 += 32) {
        f16x8 af[4];
#pragma unroll
        for (int m = 0; m < 4; ++m) {
            f16x8 h;
            h[0] = (_Float16)avA[2*m][0];   h[1] = (_Float16)avA[2*m][1];
            h[2] = (_Float16)avA[2*m][2];   h[3] = (_Float16)avA[2*m][3];
            h[4] = (_Float16)avA[2*m+1][0]; h[5] = (_Float16)avA[2*m+1][1];
            h[6] = (_Float16)avA[2*m+1][2]; h[7] = (_Float16)avA[2*m+1][3];
            af[m] = h;
        }
        if (k0 + 32 < 256) loadA(k0 + 32);    // prefetch next tile into regs
#pragma unroll
        for (int nt = 0; nt < 8; ++nt) {
            const f16x8 bf = *(const f16x8*)&Bs[nt * 16 + m16][k0 + quad * 8];
#pragma unroll
            for (int m = 0; m < 4; ++m)
                acc[m][nt] = __builtin_amdgcn_mfma_f32_16x16x32_f16(af[m], bf, acc[m][nt], 0, 0, 0);
        }
    }

    // ---- epilogue: C/D layout col=lane&15, row=quad*4+r (verified convention)
#pragma unroll
    for (int m = 0; m < 4; ++m)
#pragma unroll
        for (int nt = 0; nt < 8; ++nt)
#pragma unroll
            for (int r = 0; r < 4; ++r) {
                const int gm = rowBase + m * 16 + quad * 4 + r;
                if (gm < N) H[(size_t)gm * 128 + nt * 16 + m16] = (_Float16)acc[m][nt][r];
            }
}

// ---------------------------------------------------------------- Fused agg1 + gemm2
// Round-21: counters (103us, VALU 45%, FETCH 193MB, occ 75%) showed mixed
// VALU+latency bound. Three fixes, math bit-identical:
//  (1) n forced to SGPR via readfirstlane -> edge index wave-uniform ->
//      colc[rpn+e] and dinv[s] become SCALAR loads: all edge-loop shfls gone.
//  (2) the 64-address uncoalesced cnt[sv] lane-gather + per-lane rsqrt gone
//      (dinv precomputed in fill_csr).
//  (3) prefetch depth 4 -> 8 (VGPR was 20: huge headroom) for 2x MLP.
__global__ __launch_bounds__(256) void agg1_gemm2(const _Float16* __restrict__ H,
                                                  const int* __restrict__ cnt,
                                                  const int* __restrict__ rp,
                                                  const int* __restrict__ colc,
                                                  const float* __restrict__ dinv,
                                                  const float* __restrict__ b1,
                                                  const float* __restrict__ W2,
                                                  float* __restrict__ Z) {
    const int nw   = (blockIdx.x * blockDim.x + threadIdx.x) >> 6;
    const int lane = threadIdx.x & 63;
    if (nw >= N) return;
    const int n   = __builtin_amdgcn_readfirstlane(nw);
    const int c   = min(__builtin_amdgcn_readfirstlane(cnt[n]), CAP);
    const int rpn = __builtin_amdgcn_readfirstlane(rp[n]);
    const float dn = dinv[n];

    const _Float16* hbase = H + lane * 2;

    // hoist epilogue operands above the edge loop (overlap their latency)
    const float2 b   = *(const float2*)&b1[lane * 2];
    const float4 wa0 = *(const float4*)&W2[(size_t)(lane * 2) * 8];
    const float4 wa1 = *(const float4*)&W2[(size_t)(lane * 2) * 8 + 4];
    const float4 wb0 = *(const float4*)&W2[(size_t)(lane * 2 + 1) * 8];
    const float4 wb1 = *(const float4*)&W2[(size_t)(lane * 2 + 1) * 8 + 4];

    // edge e in [0, c]: src = e<c ? colc[rpn+e] : n (self-loop); weight dinv[src]
    f16x2 va[8]; float wa[8];
#pragma unroll
    for (int t = 0; t < 8; ++t) {
        const int ec = t < c ? t : c;              // uniform clamp
        const int s  = (ec < c) ? colc[rpn + ec] : n;
        wa[t] = (t <= c) ? dinv[s] : 0.f;
        va[t] = *(const f16x2*)&hbase[(size_t)s * 128];
    }
    float ax = 0.f, ay = 0.f;
    const int tot8 = (c + 1 + 7) & ~7;
    for (int j = 8; j < tot8; j += 8) {
        f16x2 vb[8]; float wb[8];
#pragma unroll
        for (int t = 0; t < 8; ++t) {
            const int e  = j + t;
            const int ec = e < c ? e : c;
            const int s  = (ec < c) ? colc[rpn + ec] : n;
            wb[t] = (e <= c) ? dinv[s] : 0.f;
            vb[t] = *(const f16x2*)&hbase[(size_t)s * 128];
        }
#pragma unroll
        for (int t = 0; t < 8; ++t) {
            ax = fmaf(wa[t], (float)va[t][0], ax);
            ay = fmaf(wa[t], (float)va[t][1], ay);
            va[t] = vb[t]; wa[t] = wb[t];
        }
    }
#pragma unroll
    for (int t = 0; t < 8; ++t) {
        ax = fmaf(wa[t], (float)va[t][0], ax);
        ay = fmaf(wa[t], (float)va[t][1], ay);
    }

    const float hr0 = fmaxf(ax * dn + b.x, 0.f);
    const float hr1 = fmaxf(ay * dn + b.y, 0.f);

    float p[8];
    p[0] = hr0 * wa0.x + hr1 * wb0.x;
    p[1] = hr0 * wa0.y + hr1 * wb0.y;
    p[2] = hr0 * wa0.z + hr1 * wb0.z;
    p[3] = hr0 * wa0.w + hr1 * wb0.w;
    p[4] = hr0 * wa1.x + hr1 * wb1.x;
    p[5] = hr0 * wa1.y + hr1 * wb1.y;
    p[6] = hr0 * wa1.z + hr1 * wb1.z;
    p[7] = hr0 * wa1.w + hr1 * wb1.w;
#pragma unroll
    for (int off = 32; off > 0; off >>= 1)
#pragma unroll
        for (int j = 0; j < 8; ++j) p[j] += __shfl_xor(p[j], off);
    if (lane == 0) {
        *(float4*)&Z[(size_t)n * 8]     = make_float4(p[0], p[1], p[2], p[3]);
        *(float4*)&Z[(size_t)n * 8 + 4] = make_float4(p[4], p[5], p[6], p[7]);
    }
}

// ---------------------------------------------------------------- Aggregation layer 2 (F=8)
// 8 lanes per node (lane=feat): 12.5K waves, Z-row read = one coalesced 32B
// request per octet, colc/dinv loads same-address broadcasts within octet.
// Round-21: dinv load replaces cnt load + rsqrt.
__global__ __launch_bounds__(256) void agg2(const float* __restrict__ Z,
                                            const int* __restrict__ cnt,
                                            const int* __restrict__ rp,
                                            const int* __restrict__ colc,
                                            const float* __restrict__ dinv,
                                            const float* __restrict__ b2,
                                            float* __restrict__ ZA) {
    const int t = blockIdx.x * blockDim.x + threadIdx.x;
    const int n = t >> 3;              // node
    const int f = t & 7;               // feature
    if (n >= N) return;
    const int c   = min(cnt[n], CAP);
    const int rpn = rp[n];

    float acc = 0.f;
    float zv[4], wv[4];
#pragma unroll
    for (int tt = 0; tt < 4; ++tt) {
        const int s = (tt < c) ? colc[rpn + tt] : n;
        wv[tt] = (tt < c) ? dinv[s] : 0.0f;
        zv[tt] = Z[(size_t)s * 8 + f];
    }
    for (int j = 4; j + 4 <= c + 4; j += 4) {
        float zb[4], wb[4];
#pragma unroll
        for (int tt = 0; tt < 4; ++tt) {
            const int jt = j + tt;
            const int s  = (jt < c) ? colc[rpn + jt] : n;
            wb[tt] = (jt < c) ? dinv[s] : 0.0f;
            zb[tt] = Z[(size_t)s * 8 + f];
        }
#pragma unroll
        for (int tt = 0; tt < 4; ++tt) {
            acc = fmaf(wv[tt], zv[tt], acc);
            zv[tt] = zb[tt]; wv[tt] = wb[tt];
        }
    }
#pragma unroll
    for (int tt = 0; tt < 4; ++tt) acc = fmaf(wv[tt], zv[tt], acc);

    const float dn = dinv[n];
    const float zn = Z[(size_t)n * 8 + f];
    ZA[(size_t)n * 8 + f] = (acc + dn * zn) * dn + b2[f];
}

// ---------------------------------------------------------------- Edge scoring
__global__ __launch_bounds__(256) void score(const float* __restrict__ ZA,
                                             const int* __restrict__ pe,
                                             const int* __restrict__ ne,
                                             float* __restrict__ out) {
    const int e = blockIdx.x * blockDim.x + threadIdx.x;
    if (e >= ES) return;
    int a, b;
    if (e < EP) { a = pe[e];      b = pe[EP + e]; }
    else        { a = ne[e - EP]; b = ne[e];      }
    const float4 xa0 = *(const float4*)&ZA[(size_t)a * 8];
    const float4 xa1 = *(const float4*)&ZA[(size_t)a * 8 + 4];
    const float4 xb0 = *(const float4*)&ZA[(size_t)b * 8];
    const float4 xb1 = *(const float4*)&ZA[(size_t)b * 8 + 4];
    out[e] = xa0.x * xb0.x + xa0.y * xb0.y + xa0.z * xb0.z + xa0.w * xb0.w +
             xa1.x * xb1.x + xa1.y * xb1.y + xa1.z * xb1.z + xa1.w * xb1.w;
}

// ---------------------------------------------------------------- launch

extern "C" void kernel_launch(void* const* d_in, const int* in_sizes, int n_in,
                              void* d_out, int out_size, void* d_ws, size_t ws_size,
                              hipStream_t stream) {
    const float* x  = (const float*)d_in[0];
    const int*   ei = (const int*)d_in[1];   // [2, 1.6M] row-major
    const int*   pe = (const int*)d_in[2];   // [2, 200k]
    const int*   ne = (const int*)d_in[3];   // [2, 200k]
    const float* W1 = (const float*)d_in[4];
    const float* b1 = (const float*)d_in[5];
    const float* W2 = (const float*)d_in[6];
    const float* b2 = (const float*)d_in[7];
    float* out = (float*)d_out;

    char* ws = (char*)d_ws;
    size_t off = 0;
    auto carve = [&](size_t bytes) {
        char* p = ws + off;
        off += (bytes + 255) & ~(size_t)255;
        return p;
    };
    int*       gcnt = (int*)      carve((size_t)XG2 * sizeof(int));          // 512 B
    int*       cnt  = (int*)      carve((size_t)N * sizeof(int));            // 0.4 MB (fully written by fill_csr)
    int*       rp   = (int*)      carve((size_t)N * sizeof(int));            // 0.4 MB
    float*     dinv = (float*)    carve((size_t)N * sizeof(float));          // 0.4 MB
    unsigned*  eb   = (unsigned*) carve((size_t)XG2 * SEGCAP * sizeof(unsigned)); // 7.0 MB
    int*       colc = (int*)      carve((size_t)XG2 * SEGCAP * sizeof(int)); // 7.0 MB (CSR col)
    _Float16*  H    = (_Float16*) carve((size_t)N * 128 * sizeof(_Float16)); // 25.6 MB
    float*     Z    = (float*)    carve((size_t)N * 8 * sizeof(float));      // 3.2 MB
    float*     ZA   = (float*)    carve((size_t)N * 8 * sizeof(float));      // 3.2 MB
    _Float16*  W1T  = (_Float16*) carve((size_t)128 * 256 * sizeof(_Float16)); // 64 KB

    hipMemsetAsync(gcnt, 0, (size_t)XG2 * sizeof(int), stream);
    partition_edges<<<NPB, PBS, 0, stream>>>(ei, gcnt, eb);
    w1_transpose   <<<128, 256, 0, stream>>>(W1, W1T);
    fill_csr       <<<XG2, 1024, 0, stream>>>(eb, gcnt, cnt, rp, dinv, colc);
    gemm1_mfma     <<<(N + 255) / 256, 256, 0, stream>>>(x, W1T, H);
    agg1_gemm2     <<<((size_t)N * 64 + 255) / 256, 256, 0, stream>>>(H, cnt, rp, colc, dinv, b1, W2, Z);
    agg2           <<<((size_t)N * 8 + 255) / 256, 256, 0, stream>>>(Z, cnt, rp, colc, dinv, b2, ZA);
    score          <<<(ES + 255) / 256, 256, 0, stream>>>(ZA, pe, ne, out);
}